// Round 10
// baseline (84.984 us; speedup 1.0000x reference)
//
#include <hip/hip_runtime.h>

#define NB 8192
#define ND 128
#define NC 1000
#define NJB 64    // j-blocks (128 j each)
#define JBS 128   // j-rows per block
#define NIS 32    // i-slices (256 i each)
#define CAP 64    // bucket capacity per class

typedef __attribute__((ext_vector_type(8))) short bf16x8;
typedef __attribute__((ext_vector_type(4))) float f32x4;

__device__ __forceinline__ unsigned short f2bf(float f) {
    unsigned int u = __float_as_uint(f);
    return (unsigned short)((u + 0x7fffu + ((u >> 16) & 1u)) >> 16);
}

// ---------------- CE (label smoothing) fused with emb->bf16 conversion + cnt zeroing ---------
__global__ __launch_bounds__(256) void ce_prep_kernel(const float* __restrict__ logits,
                                                      const float* __restrict__ emb,
                                                      const int* __restrict__ labels,
                                                      unsigned short* __restrict__ ebf,
                                                      float* __restrict__ cls_part,
                                                      int* __restrict__ cnt) {
    int wave = threadIdx.x >> 6, lane = threadIdx.x & 63;
    int r = blockIdx.x * 4 + wave;

    // zero the class-count array (bucket_kernel runs after us in stream order)
    if (blockIdx.x == 0) {
        for (int k = threadIdx.x; k < NC; k += 256) cnt[k] = 0;
    }

    {
        const float* erow = emb + (size_t)r * ND;
        float2 v = *(const float2*)(erow + lane * 2);
        unsigned int packed = (unsigned int)f2bf(v.x) | ((unsigned int)f2bf(v.y) << 16);
        *(unsigned int*)(ebf + (size_t)r * ND + lane * 2) = packed;
    }

    const float* x = logits + (size_t)r * NC;
    float4 q0 = *(const float4*)(x + 4 * lane);
    float4 q1 = *(const float4*)(x + 256 + 4 * lane);
    float4 q2 = *(const float4*)(x + 512 + 4 * lane);
    float4 q3;
    bool a3 = (192 + lane) < 250;
    if (a3) q3 = *(const float4*)(x + 768 + 4 * lane);
    else q3 = make_float4(-3.4e38f, -3.4e38f, -3.4e38f, -3.4e38f);

    float m = fmaxf(fmaxf(fmaxf(q0.x, q0.y), fmaxf(q0.z, q0.w)),
                    fmaxf(fmaxf(q1.x, q1.y), fmaxf(q1.z, q1.w)));
    m = fmaxf(m, fmaxf(fmaxf(q2.x, q2.y), fmaxf(q2.z, q2.w)));
    m = fmaxf(m, fmaxf(fmaxf(q3.x, q3.y), fmaxf(q3.z, q3.w)));
    float s = (q0.x + q0.y + q0.z + q0.w) + (q1.x + q1.y + q1.z + q1.w) +
              (q2.x + q2.y + q2.z + q2.w) +
              (a3 ? (q3.x + q3.y + q3.z + q3.w) : 0.f);
#pragma unroll
    for (int o = 32; o >= 1; o >>= 1) {
        m = fmaxf(m, __shfl_xor(m, o));
        s += __shfl_xor(s, o);
    }
    float se = expf(q0.x - m) + expf(q0.y - m) + expf(q0.z - m) + expf(q0.w - m) +
               expf(q1.x - m) + expf(q1.y - m) + expf(q1.z - m) + expf(q1.w - m) +
               expf(q2.x - m) + expf(q2.y - m) + expf(q2.z - m) + expf(q2.w - m) +
               expf(q3.x - m) + expf(q3.y - m) + expf(q3.z - m) + expf(q3.w - m);
#pragma unroll
    for (int o = 32; o >= 1; o >>= 1) se += __shfl_xor(se, o);
    float xl = x[labels[r]];
    float v = (m + logf(se)) - 0.9f * xl - 0.1f * (s * (1.0f / NC));
    if (lane == 0) cls_part[r] = v;
}

// ---------------- bucket: per-class row lists (order nondeterministic, consumers tie-break) ---
__global__ __launch_bounds__(256) void bucket_kernel(const int* __restrict__ labels,
                                                     int* __restrict__ cnt,
                                                     int* __restrict__ lists) {
    int r = blockIdx.x * 256 + threadIdx.x;
    int c = labels[r];
    int slot = atomicAdd(&cnt[c], 1);
    if (slot < CAP) lists[c * CAP + slot] = r;
}

// ---------------- mining: zero-barrier static-LDS; value-only neg tracking ----------------
// MEASUREMENT ROUND: the compute sweep runs 2x (idempotent max-merge; memory fence blocks CSE)
// so this dispatch's duration = 2x true cost and it ranks above the harness poison fills,
// exposing its counters. Algorithm is byte-identical to R9 otherwise.
__global__ __launch_bounds__(256) void mine_kernel(const unsigned short* __restrict__ ebf,
                                                   const int* __restrict__ labels,
                                                   float* __restrict__ part) {
    __shared__ unsigned short btile[JBS * ND];  // 32 KB, static after prologue
    int tid = threadIdx.x;
    int wave = tid >> 6, lane = tid & 63;
    int col = lane & 15, grp = lane >> 4;
    int jblk = blockIdx.x, jbase = jblk * JBS;
    int ibase = blockIdx.y * 256 + wave * 64;

    // stage 128 j-rows: XOR-swizzled global source -> linear LDS dest (rule #21)
#pragma unroll
    for (int rep = 0; rep < 8; ++rep) {
        int row = (tid >> 4) + rep * 16;
        const unsigned short* src =
            ebf + (size_t)(jbase + row) * ND + (((tid & 15) ^ (row & 7)) << 3);
        unsigned short* dst = btile + (size_t)(wave * 4 + rep * 16) * ND;
        __builtin_amdgcn_global_load_lds(
            (const __attribute__((address_space(1))) unsigned int*)src,
            (__attribute__((address_space(3))) unsigned int*)dst, 16, 0, 0);
    }

    // A fragments: 4 i-chunks x 4 k-chunks, registers for whole kernel
    bf16x8 af[4][4];
#pragma unroll
    for (int ic = 0; ic < 4; ++ic) {
        const unsigned short* ap = ebf + (size_t)(ibase + ic * 16 + col) * ND + (grp << 3);
#pragma unroll
        for (int kc = 0; kc < 4; ++kc) af[ic][kc] = *(const bf16x8*)(ap + kc * 32);
    }
    int li[16];
#pragma unroll
    for (int ic = 0; ic < 4; ++ic)
#pragma unroll
        for (int r = 0; r < 4; ++r) li[ic * 4 + r] = labels[ibase + ic * 16 + grp * 4 + r];
    int ljs[8];
#pragma unroll
    for (int st = 0; st < 8; ++st) ljs[st] = labels[jbase + st * 16 + col];

    float bn[16];
#pragma unroll
    for (int k = 0; k < 16; ++k) bn[k] = -3.4e38f;

    __syncthreads();  // the ONLY barrier: stage drained (vmcnt0+lgkm0), waves free-run after

#pragma unroll 1
    for (int rep2 = 0; rep2 < 2; ++rep2) {
        asm volatile("" ::: "memory");  // block CSE across reps: LDS re-read, MFMA recomputed
#pragma unroll
        for (int st = 0; st < 8; ++st) {
            bf16x8 bfr[4];
#pragma unroll
            for (int kc = 0; kc < 4; ++kc) {
                int chunk = (grp + 4 * kc) ^ (col & 7);
                bfr[kc] = *(const bf16x8*)(btile + (size_t)(st * 16 + col) * ND + chunk * 8);
            }
            f32x4 acc[4] = {{0.f, 0.f, 0.f, 0.f}, {0.f, 0.f, 0.f, 0.f},
                            {0.f, 0.f, 0.f, 0.f}, {0.f, 0.f, 0.f, 0.f}};
#pragma unroll
            for (int kc = 0; kc < 4; ++kc)
#pragma unroll
                for (int ic = 0; ic < 4; ++ic)
                    acc[ic] = __builtin_amdgcn_mfma_f32_16x16x32_bf16(af[ic][kc], bfr[kc],
                                                                      acc[ic], 0, 0, 0);
            int lj = ljs[st];
#pragma unroll
            for (int ic = 0; ic < 4; ++ic)
#pragma unroll
                for (int r = 0; r < 4; ++r)
                    bn[ic * 4 + r] =
                        fmaxf(bn[ic * 4 + r], (lj == li[ic * 4 + r]) ? -3.4e38f : acc[ic][r]);
        }
    }

    // max over the 16 columns (lanes sharing grp)
#pragma unroll
    for (int k = 0; k < 16; ++k)
#pragma unroll
        for (int msk = 1; msk <= 8; msk <<= 1)
            bn[k] = fmaxf(bn[k], __shfl_xor(bn[k], msk));
    if (col == 0) {
#pragma unroll
        for (int ic = 0; ic < 4; ++ic)
#pragma unroll
            for (int r = 0; r < 4; ++r) {
                int gi = ibase + ic * 16 + grp * 4 + r;
                part[((size_t)gi << 6) + jblk] = bn[ic * 4 + r];
            }
    }
}

// ---------------- reduce: neg from mined value; pos exact via class bucket ----------------
__global__ __launch_bounds__(256) void reduce_kernel(const float* __restrict__ e,
                                                     const int* __restrict__ labels,
                                                     const float* __restrict__ part,
                                                     const int* __restrict__ cnt,
                                                     const int* __restrict__ lists,
                                                     float2* __restrict__ tri_part) {
    int wave = threadIdx.x >> 6, lane = threadIdx.x & 63;
    int r = blockIdx.x * 4 + wave;

    // merge 64 neg partials (value-only max, fully associative)
    float nb = part[((size_t)r << 6) + lane];
#pragma unroll
    for (int o = 1; o <= 32; o <<= 1) nb = fmaxf(nb, __shfl_xor(nb, o));
    float d_an = sqrtf(fmaxf(2.0f - 2.0f * nb, 0.0f));

    int myl = labels[r];
    int ctot = cnt[myl];
    int n = min(ctot, CAP);
    const float* a = e + (size_t)r * ND;
    float2 av = *(const float2*)(a + lane * 2);

    // exact fp32 argmax over same-class candidates; (d2, smaller-j) tie-break makes the
    // result independent of the bucket's atomic fill order
    float best = -1.0f;
    int jp = r;
    for (int k = 0; k < n; ++k) {
        int j2 = lists[myl * CAP + k];  // wave-uniform
        if (j2 == r) continue;
        const float* p = e + (size_t)j2 * ND;
        float2 pv = *(const float2*)(p + lane * 2);
        float dx = av.x - pv.x, dy = av.y - pv.y;
        float ss = dx * dx + dy * dy;
#pragma unroll
        for (int o = 32; o >= 1; o >>= 1) ss += __shfl_xor(ss, o);
        if (ss > best || (ss == best && j2 < jp)) { best = ss; jp = j2; }
    }
    bool valid = (ctot >= 2) && (ctot < NB);

    // winner recomputed with torch's +eps inside the norm (jp==r when none: unused)
    const float* p = e + (size_t)jp * ND;
    float2 pv = *(const float2*)(p + lane * 2);
    float dx = av.x - pv.x + 1e-6f, dy = av.y - pv.y + 1e-6f;
    float ss = dx * dx + dy * dy;
#pragma unroll
    for (int o = 32; o >= 1; o >>= 1) ss += __shfl_xor(ss, o);
    float d_ap = sqrtf(ss);

    if (lane == 0) {
        float per = valid ? fmaxf(d_ap - d_an + 0.5f, 0.0f) : 0.0f;
        tri_part[r] = make_float2(per, valid ? 1.0f : 0.0f);
    }
}

// ---------------- final combine: single block tree-reduces all partials ----------------
__global__ __launch_bounds__(1024) void fin_kernel(const float* __restrict__ cls_part,
                                                   const float2* __restrict__ tri_part,
                                                   float* __restrict__ out) {
    __shared__ float sc[16], sp[16], sn[16];
    int t = threadIdx.x;
    int wave = t >> 6, lane = t & 63;
    float c = 0.f, tp = 0.f, tc = 0.f;
    for (int k = t; k < NB; k += 1024) {
        c += cls_part[k];
        float2 q = tri_part[k];
        tp += q.x;
        tc += q.y;
    }
#pragma unroll
    for (int o = 32; o >= 1; o >>= 1) {
        c += __shfl_xor(c, o);
        tp += __shfl_xor(tp, o);
        tc += __shfl_xor(tc, o);
    }
    if (lane == 0) { sc[wave] = c; sp[wave] = tp; sn[wave] = tc; }
    __syncthreads();
    if (t == 0) {
        float C = 0.f, P = 0.f, V = 0.f;
        for (int w = 0; w < 16; ++w) { C += sc[w]; P += sp[w]; V += sn[w]; }
        float cls = C * (1.0f / NB);
        float tri = V > 0.5f ? P / V : 0.0f;
        out[0] = cls + tri;
    }
}

extern "C" void kernel_launch(void* const* d_in, const int* in_sizes, int n_in,
                              void* d_out, int out_size, void* d_ws, size_t ws_size,
                              hipStream_t stream) {
    const float* logits = (const float*)d_in[0];
    const float* emb = (const float*)d_in[1];
    const int* labels = (const int*)d_in[2];

    char* w = (char*)d_ws;
    unsigned short* ebf = (unsigned short*)w;                              // 2 MB
    float* part = (float*)(w + (size_t)NB * ND * 2);                       // NB*64 f32 (2 MB)
    float* cls_part = (float*)(w + 4194304);                               // NB f32 (32 KB)
    float2* tri_part = (float2*)(w + 4194304 + 32768);                     // NB f32x2 (64 KB)
    int* cnt = (int*)(w + 4194304 + 32768 + 65536);                        // NC int (4 KB)
    int* lists = (int*)(w + 4194304 + 32768 + 65536 + 4096);               // NC*CAP int (256 KB)

    // MEASUREMENT: ce_prep launched twice (idempotent) -> its cost = total_R10 - total_R9 - mine/2
    ce_prep_kernel<<<NB / 4, 256, 0, stream>>>(logits, emb, labels, ebf, cls_part, cnt);
    ce_prep_kernel<<<NB / 4, 256, 0, stream>>>(logits, emb, labels, ebf, cls_part, cnt);
    bucket_kernel<<<NB / 256, 256, 0, stream>>>(labels, cnt, lists);
    mine_kernel<<<dim3(NJB, NIS), 256, 0, stream>>>(ebf, labels, part);
    reduce_kernel<<<NB / 4, 256, 0, stream>>>(emb, labels, part, cnt, lists, tri_part);
    fin_kernel<<<1, 1024, 0, stream>>>(cls_part, tri_part, (float*)d_out);
}